// Round 1
// baseline (190.278 us; speedup 1.0000x reference)
//
#include <hip/hip_runtime.h>
#include <hip/hip_bf16.h>

// Problem dims (fixed): B=2, M=L=2048, H=1024, K_HEADS=16, D=64
// All inputs/output are FLOAT32; compute in bf16 MFMA with f32 accumulation.
// Algebra: softmax branch is dead; out = Q (K^T V) blockdiag Wo^T.
// Round 10 (Gram refactor): T_h = K_h^T V_h = Wk_h (hc^T hc) Wv_h^T, so:
//   G_b   = hcT_b @ hcT_b^T            (NT, M=N=1024, K=2048)  8.6 GF
//   V2T_b = Wv @ G_b                   (NT, 1024^3)            4.3 GF
//   T_h   = Wk_h @ V2T_h^T             (NT, 64x64x1024/head)   0.27 GF  -> Sbuf (f32, no atomics)
//   W2[n][h*64+dp] = sum_d Wo[n][h*64+d] T[h][dp][d]
//   F_b = W2_b @ Wq ;  out_b = h_b @ F_b^T
// Replaces the old fused gemm_kvt (34.4 GF + 2M atomics) with 13.2 GF.
#define BB 2
#define MM 2048
#define HH 1024
#define KH 16

typedef short s16x8 __attribute__((ext_vector_type(8)));
typedef float f32x4 __attribute__((ext_vector_type(4)));
typedef float f32x16 __attribute__((ext_vector_type(16)));

#define GLOBAL_AS __attribute__((address_space(1)))
#define LDS_AS    __attribute__((address_space(3)))

__device__ __forceinline__ void async_copy16(const void* g, void* l) {
    __builtin_amdgcn_global_load_lds((const GLOBAL_AS void*)g, (LDS_AS void*)l, 16, 0, 0);
}

struct __align__(8) bf16x4_t { __hip_bfloat16 x, y, z, w; };

// ---------------------------------------------------------------------------
// fused prep: fp32->bf16 converts + hc transpose + Wq transpose: grid (4096, 6)
// seg 0: convert h            (4096 blocks)
// seg 1: transpose-convert hc -> hcT [b][k][m]   (1024 tiles of 64x64)
// seg 2/3/4: convert Wk/Wv/Wo (1024 blocks each)
// seg 5: transpose-convert Wq -> WqT             (256 tiles)
// ---------------------------------------------------------------------------
__global__ __launch_bounds__(256) void cvt_all(
    const float* __restrict__ h_f, const float* __restrict__ hc_f,
    const float* __restrict__ Wk_f, const float* __restrict__ Wv_f,
    const float* __restrict__ Wo_f, const float* __restrict__ Wq_f,
    __hip_bfloat16* __restrict__ hb, __hip_bfloat16* __restrict__ hcT,
    __hip_bfloat16* __restrict__ wkb, __hip_bfloat16* __restrict__ wvb,
    __hip_bfloat16* __restrict__ wob, __hip_bfloat16* __restrict__ wqt)
{
    __shared__ float Tl[64][65];
    const int seg = blockIdx.y;
    const int t = threadIdx.x;
    const int bx = blockIdx.x;

    if (seg == 1) {                        // hc -> hcT (per-b [1024][2048])
        if (bx >= BB * 512) return;
        const int b = bx >> 9;
        const int tile = bx & 511;
        const int m0 = (tile >> 4) * 64;   // 32 m-tiles
        const int k0 = (tile & 15) * 64;   // 16 k-tiles
        const int r = t >> 6;
        const int c = t & 63;
        const float* src = hc_f + (size_t)b * MM * HH;
#pragma unroll
        for (int i = 0; i < 64; i += 4)
            Tl[r + i][c] = src[(size_t)(m0 + r + i) * HH + k0 + c];
        __syncthreads();
        __hip_bfloat16* dst = hcT + (size_t)b * HH * MM;
#pragma unroll
        for (int i = 0; i < 64; i += 4)
            dst[(size_t)(k0 + r + i) * MM + m0 + c] = __float2bfloat16(Tl[c][r + i]);
        return;
    }
    if (seg == 5) {                        // Wq -> WqT
        if (bx >= 256) return;
        const int j0 = (bx >> 4) * 64;
        const int k0 = (bx & 15) * 64;
        const int r = t >> 6;
        const int c = t & 63;
#pragma unroll
        for (int i = 0; i < 64; i += 4)
            Tl[r + i][c] = Wq_f[(size_t)(j0 + r + i) * HH + k0 + c];
        __syncthreads();
#pragma unroll
        for (int i = 0; i < 64; i += 4)
            wqt[(size_t)(k0 + r + i) * HH + j0 + c] = __float2bfloat16(Tl[c][r + i]);
        return;
    }
    const float* src;
    __hip_bfloat16* dst;
    int n;
    switch (seg) {
        case 0: src = h_f;  dst = hb;  n = BB * MM * HH; break;
        case 2: src = Wk_f; dst = wkb; n = HH * HH; break;
        case 3: src = Wv_f; dst = wvb; n = HH * HH; break;
        default: src = Wo_f; dst = wob; n = HH * HH; break;
    }
    const int i = (bx * 256 + t) * 4;
    if (i + 3 < n) {
        const float4 v = *(const float4*)(src + i);
        bf16x4_t o;
        o.x = __float2bfloat16(v.x);
        o.y = __float2bfloat16(v.y);
        o.z = __float2bfloat16(v.z);
        o.w = __float2bfloat16(v.w);
        *(bf16x4_t*)(dst + i) = o;
    }
}

// ---------------------------------------------------------------------------
// store helpers
// ---------------------------------------------------------------------------
__device__ __forceinline__ void store_c(__hip_bfloat16* C, size_t idx, float v) {
    C[idx] = __float2bfloat16(v);
}
__device__ __forceinline__ void store_c(float* C, size_t idx, float v) { C[idx] = v; }

// ---------------------------------------------------------------------------
// 64x128-tile BK=64 NT GEMM body, generalized over K-depth (KD) and C stride.
// (structure verified rounds 7-9; KD/ldc generalization this round)
// ---------------------------------------------------------------------------
template <typename OutT, int KD>
__device__ __forceinline__ void gemm_nt_body64(
    const __hip_bfloat16* __restrict__ A,
    const __hip_bfloat16* __restrict__ Bm,
    OutT* __restrict__ C,
    __hip_bfloat16* As, __hip_bfloat16* Bs,
    int m0, int n0, int ldc)
{
    const int t    = threadIdx.x;
    const int lane = t & 63;
    const int wave = t >> 6;

    const int srow = lane >> 3;
    const int sw   = ((lane & 7) ^ srow) * 8;

    const int wn  = wave * 32;
    const int fm  = lane & 31;
    const int fm7 = fm & 7;
    const int ghi = lane >> 5;

    f32x16 acc[2] = {};

    for (int k0 = 0; k0 < KD; k0 += 64) {
        __syncthreads();
        {
            const __hip_bfloat16* ag = A + (size_t)(m0 + wave * 16 + srow) * KD + k0 + sw;
            async_copy16(ag,          As + wave * 1024);
            async_copy16(ag + 8 * KD, As + wave * 1024 + 512);
        }
#pragma unroll
        for (int i = 0; i < 2; ++i) {
            const int c = wave * 2 + i;
            const __hip_bfloat16* bg = Bm + (size_t)(n0 + c * 16 + srow) * KD + k0 + sw;
            async_copy16(bg,          Bs + c * 1024);
            async_copy16(bg + 8 * KD, Bs + c * 1024 + 512);
        }
        __syncthreads();

#pragma unroll
        for (int ks = 0; ks < 64; ks += 16) {
            const int pos = ((((ks >> 3) + ghi) ^ fm7) * 8);
            s16x8 af[2], bf;
#pragma unroll
            for (int mi = 0; mi < 2; ++mi)
                af[mi] = *(const s16x8*)(As + (mi * 32 + fm) * 64 + pos);
            bf = *(const s16x8*)(Bs + (wn + fm) * 64 + pos);
#pragma unroll
            for (int mi = 0; mi < 2; ++mi)
                acc[mi] = __builtin_amdgcn_mfma_f32_32x32x16_bf16(
                    af[mi], bf, acc[mi], 0, 0, 0);
        }
    }

    const int ec = lane & 31;
    const int eb = (lane >> 5) * 4;
#pragma unroll
    for (int mi = 0; mi < 2; ++mi)
#pragma unroll
        for (int r = 0; r < 16; ++r) {
            const int m = m0 + mi * 32 + (r & 3) + 8 * (r >> 2) + eb;
            const int n = n0 + wn + ec;
            store_c(C, (size_t)m * ldc + n, acc[mi][r]);
        }
}

// G_b = hcT_b @ hcT_b^T (Gram), bf16 out: grid (16, 8, 2)
__global__ __launch_bounds__(256) void gemm_g(
    const __hip_bfloat16* __restrict__ hcT, __hip_bfloat16* __restrict__ G)
{
    __shared__ __align__(16) __hip_bfloat16 As[64 * 64];
    __shared__ __align__(16) __hip_bfloat16 Bs[128 * 64];
    const int b = blockIdx.z;
    const __hip_bfloat16* Ab = hcT + (size_t)b * HH * MM;
    gemm_nt_body64<__hip_bfloat16, MM>(Ab, Ab, G + (size_t)b * HH * HH,
                                       As, Bs, blockIdx.x * 64, blockIdx.y * 128, HH);
}

// V2T_b = Wv @ G_b  (V2T[d][k] = sum_k' Wv[d][k'] G[k][k']): grid (16, 8, 2)
__global__ __launch_bounds__(256) void gemm_v2(
    const __hip_bfloat16* __restrict__ wvb, const __hip_bfloat16* __restrict__ G,
    __hip_bfloat16* __restrict__ V2T)
{
    __shared__ __align__(16) __hip_bfloat16 As[64 * 64];
    __shared__ __align__(16) __hip_bfloat16 Bs[128 * 64];
    const int b = blockIdx.z;
    gemm_nt_body64<__hip_bfloat16, HH>(wvb, G + (size_t)b * HH * HH,
                                       V2T + (size_t)b * HH * HH,
                                       As, Bs, blockIdx.x * 64, blockIdx.y * 128, HH);
}

// T_h = NT(Wk_h, V2T_h): per (head,b), 64x64 out (f32, direct store, no atomics)
// grid (KH, BB), block 256 (4 waves, one 32x32 MFMA tile each)
__global__ __launch_bounds__(256) void gemm_t(
    const __hip_bfloat16* __restrict__ wk,
    const __hip_bfloat16* __restrict__ v2t,
    float* __restrict__ S)
{
    __shared__ __align__(16) __hip_bfloat16 As[64 * 64];
    __shared__ __align__(16) __hip_bfloat16 Bs[64 * 64];
    const int t    = threadIdx.x;
    const int lane = t & 63;
    const int wave = t >> 6;
    const int head = blockIdx.x;
    const int b    = blockIdx.y;

    const __hip_bfloat16* A  = wk  + (size_t)head * 64 * HH;
    const __hip_bfloat16* Bm = v2t + (size_t)b * HH * HH + (size_t)head * 64 * HH;

    const int srow = lane >> 3;
    const int sw   = ((lane & 7) ^ srow) * 8;
    const int wm   = (wave >> 1) * 32;
    const int wn   = (wave & 1) * 32;
    const int fm   = lane & 31;
    const int fm7  = fm & 7;
    const int ghi  = lane >> 5;

    f32x16 acc = {};
    for (int k0 = 0; k0 < HH; k0 += 64) {
        __syncthreads();
#pragma unroll
        for (int i = 0; i < 2; ++i) {
            const int c = wave * 2 + i;
            async_copy16(A  + (size_t)(c * 8 + srow) * HH + k0 + sw, As + c * 512);
            async_copy16(Bm + (size_t)(c * 8 + srow) * HH + k0 + sw, Bs + c * 512);
        }
        __syncthreads();
#pragma unroll
        for (int ks = 0; ks < 64; ks += 16) {
            const int pos = ((((ks >> 3) + ghi) ^ fm7) * 8);
            const s16x8 af = *(const s16x8*)(As + (wm + fm) * 64 + pos);
            const s16x8 bf = *(const s16x8*)(Bs + (wn + fm) * 64 + pos);
            acc = __builtin_amdgcn_mfma_f32_32x32x16_bf16(af, bf, acc, 0, 0, 0);
        }
    }

    float* Sg = S + ((size_t)b * KH + head) * 4096;
    const int col   = lane & 31;
    const int rbase = 4 * (lane >> 5);
#pragma unroll
    for (int r = 0; r < 16; ++r) {
        const int row = (r & 3) + 8 * (r >> 2) + rbase;
        Sg[(wm + row) * 64 + wn + col] = acc[r];
    }
}

// F_b = W2_b @ Wq (via WqT), bf16 out: grid (16, 8, 2)
__global__ __launch_bounds__(256) void gemm_f(
    const __hip_bfloat16* __restrict__ W2, const __hip_bfloat16* __restrict__ WqT,
    __hip_bfloat16* __restrict__ F)
{
    __shared__ __align__(16) __hip_bfloat16 As[64 * 64];
    __shared__ __align__(16) __hip_bfloat16 Bs[128 * 64];
    const int b = blockIdx.z;
    gemm_nt_body64<__hip_bfloat16, HH>(W2 + (size_t)b * HH * HH, WqT,
                                       F + (size_t)b * HH * HH,
                                       As, Bs, blockIdx.x * 64, blockIdx.y * 128, HH);
}

// out_b = h_b @ F_b^T, fp32 out: grid (32, 8, 2)
__global__ __launch_bounds__(256) void gemm_final(
    const __hip_bfloat16* __restrict__ hb, const __hip_bfloat16* __restrict__ F,
    float* __restrict__ outg)
{
    __shared__ __align__(16) __hip_bfloat16 As[64 * 64];
    __shared__ __align__(16) __hip_bfloat16 Bs[128 * 64];
    const int b = blockIdx.z;
    gemm_nt_body64<float, HH>(hb + (size_t)b * MM * HH, F + (size_t)b * HH * HH,
                              outg + (size_t)b * MM * HH, As, Bs,
                              blockIdx.x * 64, blockIdx.y * 128, HH);
}

// ---------------------------------------------------------------------------
// W2[b][n][h*64+dp] = sum_d Wo[n][h*64+d] * T[b,h,dp,d]   (bf16 out)
// grid (8, KH, BB), block 256  (verified rounds 2-9)
// ---------------------------------------------------------------------------
__global__ __launch_bounds__(256) void w2_fold(
    const __hip_bfloat16* __restrict__ Wo,
    const float* __restrict__ S,
    __hip_bfloat16* __restrict__ W2)
{
    __shared__ float Sl[64 * 68];
    __shared__ float Wl[128 * 68];
    const int t = threadIdx.x, head = blockIdx.y, b = blockIdx.z;
    const int n0 = blockIdx.x * 128;

    const float* Sg = S + ((size_t)b * KH + head) * 4096;
    for (int idx = t; idx < 4096; idx += 256) {
        const int dp = idx >> 6, d = idx & 63;
        Sl[d * 68 + dp] = Sg[idx];
    }
    for (int idx = t; idx < 1024; idx += 256) {
        const int r = idx >> 3, c8 = (idx & 7) * 8;
        s16x8 wv = *(const s16x8*)(Wo + (size_t)(n0 + r) * HH + head * 64 + c8);
#pragma unroll
        for (int j = 0; j < 8; ++j) {
            __hip_bfloat16 wb = *(((const __hip_bfloat16*)&wv) + j);
            Wl[r * 68 + c8 + j] = __bfloat162float(wb);
        }
    }
    __syncthreads();

    const int dpb = (t & 15) * 4;
    const int ng  = t >> 4;
    float acc[8][4] = {};
    for (int d0 = 0; d0 < 64; d0 += 4) {
        f32x4 sv[4];
#pragma unroll
        for (int r = 0; r < 4; ++r)
            sv[r] = *(const f32x4*)(Sl + (d0 + r) * 68 + dpb);
#pragma unroll
        for (int i = 0; i < 8; ++i) {
            const f32x4 wv = *(const f32x4*)(Wl + (ng + 16 * i) * 68 + d0);
#pragma unroll
            for (int r = 0; r < 4; ++r)
#pragma unroll
                for (int j = 0; j < 4; ++j)
                    acc[i][j] += wv[r] * sv[r][j];
        }
    }

#pragma unroll
    for (int i = 0; i < 8; ++i) {
        bf16x4_t o;
        o.x = __float2bfloat16(acc[i][0]);
        o.y = __float2bfloat16(acc[i][1]);
        o.z = __float2bfloat16(acc[i][2]);
        o.w = __float2bfloat16(acc[i][3]);
        *(bf16x4_t*)(W2 + (size_t)b * HH * HH + (size_t)(n0 + ng + 16 * i) * HH
                     + head * 64 + dpb) = o;
    }
}

// ---------------------------------------------------------------------------
extern "C" void kernel_launch(void* const* d_in, const int* in_sizes, int n_in,
                              void* d_out, int out_size, void* d_ws, size_t ws_size,
                              hipStream_t stream) {
    const float* h_f  = (const float*)d_in[0];
    const float* hc_f = (const float*)d_in[1];
    // d_in[2] = key_pe: DEAD (softmax result unused by reference output)
    const float* Wq_f = (const float*)d_in[3];
    const float* Wk_f = (const float*)d_in[4];
    const float* Wv_f = (const float*)d_in[5];
    const float* Wo_f = (const float*)d_in[6];
    float* out = (float*)d_out;

    const size_t act_b = (size_t)BB * MM * HH * 2;  // 8 MB
    const size_t w_b   = (size_t)HH * HH * 2;       // 2 MB
    char* ws = (char*)d_ws;
    __hip_bfloat16* hb   = (__hip_bfloat16*)(ws);                       // 8 MB
    __hip_bfloat16* hcT  = (__hip_bfloat16*)(ws + act_b);               // 8 MB ([b][k][m])
    __hip_bfloat16* wkb  = (__hip_bfloat16*)(ws + 2 * act_b);           // 2 MB
    __hip_bfloat16* wvb  = (__hip_bfloat16*)(ws + 2 * act_b + w_b);     // 2 MB
    __hip_bfloat16* wob  = (__hip_bfloat16*)(ws + 2 * act_b + 2 * w_b); // 2 MB
    __hip_bfloat16* wqt  = (__hip_bfloat16*)(ws + 2 * act_b + 3 * w_b); // 2 MB
    __hip_bfloat16* Gb   = (__hip_bfloat16*)(ws + 2 * act_b + 4 * w_b); // 4 MB (BB x 1024^2)
    __hip_bfloat16* V2T  = (__hip_bfloat16*)(ws + 2 * act_b + 6 * w_b); // 4 MB
    float*          Sbuf = (float*)(ws + 2 * act_b + 8 * w_b);          // 512 KB
    __hip_bfloat16* W2   = (__hip_bfloat16*)(ws + 2 * act_b + 8 * w_b + (size_t)512 * 1024);   // 4 MB
    __hip_bfloat16* Fbuf = (__hip_bfloat16*)(ws + 2 * act_b + 10 * w_b + (size_t)512 * 1024);  // 4 MB

    const dim3 blk(256);

    // 0: all prep in one dispatch (converts + hc transpose + Wq transpose)
    cvt_all<<<dim3(4096, 6), blk, 0, stream>>>(h_f, hc_f, Wk_f, Wv_f, Wo_f, Wq_f,
                                               hb, hcT, wkb, wvb, wob, wqt);

    // 1: G_b = hc_b^T hc_b (Gram)
    gemm_g<<<dim3(16, 8, BB), blk, 0, stream>>>(hcT, Gb);

    // 2: V2T_b = Wv @ G_b
    gemm_v2<<<dim3(16, 8, BB), blk, 0, stream>>>(wvb, Gb, V2T);

    // 3: T_h = Wk_h @ V2T_h^T -> Sbuf (f32, direct store)
    gemm_t<<<dim3(KH, BB), blk, 0, stream>>>(wkb, V2T, Sbuf);

    // 4: W2 = blockdiag(T) folded into Wo
    w2_fold<<<dim3(8, KH, BB), blk, 0, stream>>>(wob, Sbuf, W2);

    // 5: F = W2 @ Wq (replaces the Q projection: out = h (W2 Wq)^T)
    gemm_f<<<dim3(16, 8, BB), blk, 0, stream>>>(W2, wqt, Fbuf);

    // 6: out = h @ F^T (fp32 out)
    gemm_final<<<dim3(32, 8, BB), blk, 0, stream>>>(hb, Fbuf, out);
}

// Round 2
// 177.319 us; speedup vs baseline: 1.0731x; 1.0731x over previous
//
#include <hip/hip_runtime.h>
#include <hip/hip_bf16.h>

// Problem dims (fixed): B=2, M=L=2048, H=1024, K_HEADS=16, D=64
// All inputs/output are FLOAT32; compute in bf16 MFMA with f32 accumulation.
// Algebra: softmax branch is dead; out = Q (K^T V) blockdiag Wo^T.
// Gram path: T_h = K_h^T V_h = Wk_h (hc^T hc) Wv_h^T:
//   G_b  = hcT_b @ hcT_b^T                  (NT, 1024x1024, K=2048)
//   T_h  = Wk_h G_b Wv_h^T (fused, split over k'-tiles, atomics into Sbuf)
//   W2[n][h*64+dp] = sum_d Wo[n][h*64+d] T[h][dp][d]
//   F_b = W2_b @ Wq ;  out_b = h_b @ F_b^T
// Round 11: fused v2+t (one dispatch), 64x64 tiles for g/f (2 blocks/CU),
// vectorized transpose stores, Sbuf zero back in cvt. 6 dispatches total.
#define BB 2
#define MM 2048
#define HH 1024
#define KH 16

typedef short s16x8 __attribute__((ext_vector_type(8)));
typedef float f32x4 __attribute__((ext_vector_type(4)));
typedef float f32x16 __attribute__((ext_vector_type(16)));

#define GLOBAL_AS __attribute__((address_space(1)))
#define LDS_AS    __attribute__((address_space(3)))

__device__ __forceinline__ void async_copy16(const void* g, void* l) {
    __builtin_amdgcn_global_load_lds((const GLOBAL_AS void*)g, (LDS_AS void*)l, 16, 0, 0);
}

struct __align__(8) bf16x4_t { __hip_bfloat16 x, y, z, w; };

// ---------------------------------------------------------------------------
// fused prep: fp32->bf16 converts + transposes + Sbuf zero: grid (4096, 6)
// seg 0: convert h            (4096 blocks)
// seg 1: transpose-convert hc -> hcT [b][k][m]   (1024 tiles of 64x64)
// seg 2/3/4: convert Wk/Wv/Wo (1024 blocks each)
// seg 5: bx<128 zero Sbuf; 128<=bx<384 transpose-convert Wq -> WqT
// ---------------------------------------------------------------------------
__global__ __launch_bounds__(256) void cvt_all(
    const float* __restrict__ h_f, const float* __restrict__ hc_f,
    const float* __restrict__ Wk_f, const float* __restrict__ Wv_f,
    const float* __restrict__ Wo_f, const float* __restrict__ Wq_f,
    __hip_bfloat16* __restrict__ hb, __hip_bfloat16* __restrict__ hcT,
    __hip_bfloat16* __restrict__ wkb, __hip_bfloat16* __restrict__ wvb,
    __hip_bfloat16* __restrict__ wob, __hip_bfloat16* __restrict__ wqt,
    float* __restrict__ Sz)
{
    __shared__ float Tl[64][65];
    const int seg = blockIdx.y;
    const int t = threadIdx.x;
    const int bx = blockIdx.x;

    if (seg == 1) {                        // hc -> hcT (per-b [1024][2048])
        if (bx >= BB * 512) return;
        const int b = bx >> 9;
        const int tile = bx & 511;
        const int m0 = (tile >> 4) * 64;   // 32 m-tiles
        const int k0 = (tile & 15) * 64;   // 16 k-tiles
        const int r = t >> 6;
        const int c = t & 63;
        const float* src = hc_f + (size_t)b * MM * HH;
#pragma unroll
        for (int i = 0; i < 64; i += 4)
            Tl[r + i][c] = src[(size_t)(m0 + r + i) * HH + k0 + c];
        __syncthreads();
        __hip_bfloat16* dst = hcT + (size_t)b * HH * MM;
        const int ml = (t & 15) * 4;
#pragma unroll
        for (int ii = 0; ii < 4; ++ii) {
            const int kl = (t >> 4) + 16 * ii;
            bf16x4_t o;
            o.x = __float2bfloat16(Tl[ml + 0][kl]);
            o.y = __float2bfloat16(Tl[ml + 1][kl]);
            o.z = __float2bfloat16(Tl[ml + 2][kl]);
            o.w = __float2bfloat16(Tl[ml + 3][kl]);
            *(bf16x4_t*)(dst + (size_t)(k0 + kl) * MM + m0 + ml) = o;
        }
        return;
    }
    if (seg == 5) {
        if (bx < 128) {                    // zero Sbuf: 131072 floats
            const int i = (bx * 256 + t) * 4;
            float4 z = {0.f, 0.f, 0.f, 0.f};
            *(float4*)(Sz + i) = z;
            return;
        }
        if (bx >= 384) return;             // Wq -> WqT (256 tiles)
        const int tile = bx - 128;
        const int j0 = (tile >> 4) * 64;
        const int k0 = (tile & 15) * 64;
        const int r = t >> 6;
        const int c = t & 63;
#pragma unroll
        for (int i = 0; i < 64; i += 4)
            Tl[r + i][c] = Wq_f[(size_t)(j0 + r + i) * HH + k0 + c];
        __syncthreads();
        const int ml = (t & 15) * 4;
#pragma unroll
        for (int ii = 0; ii < 4; ++ii) {
            const int kl = (t >> 4) + 16 * ii;
            bf16x4_t o;
            o.x = __float2bfloat16(Tl[ml + 0][kl]);
            o.y = __float2bfloat16(Tl[ml + 1][kl]);
            o.z = __float2bfloat16(Tl[ml + 2][kl]);
            o.w = __float2bfloat16(Tl[ml + 3][kl]);
            *(bf16x4_t*)(wqt + (size_t)(k0 + kl) * HH + j0 + ml) = o;
        }
        return;
    }
    const float* src;
    __hip_bfloat16* dst;
    int n;
    switch (seg) {
        case 0: src = h_f;  dst = hb;  n = BB * MM * HH; break;
        case 2: src = Wk_f; dst = wkb; n = HH * HH; break;
        case 3: src = Wv_f; dst = wvb; n = HH * HH; break;
        default: src = Wo_f; dst = wob; n = HH * HH; break;
    }
    const int i = (bx * 256 + t) * 4;
    if (i + 3 < n) {
        const float4 v = *(const float4*)(src + i);
        bf16x4_t o;
        o.x = __float2bfloat16(v.x);
        o.y = __float2bfloat16(v.y);
        o.z = __float2bfloat16(v.z);
        o.w = __float2bfloat16(v.w);
        *(bf16x4_t*)(dst + i) = o;
    }
}

// ---------------------------------------------------------------------------
// store helpers
// ---------------------------------------------------------------------------
__device__ __forceinline__ void store_c(__hip_bfloat16* C, size_t idx, float v) {
    C[idx] = __float2bfloat16(v);
}
__device__ __forceinline__ void store_c(float* C, size_t idx, float v) { C[idx] = v; }

// ---------------------------------------------------------------------------
// 64x64-tile BK=64 NT GEMM accumulate body (verified as gemm_t round 10):
// 4 waves, each one 32x32 quadrant; returns per-wave acc. A/B pre-offset to
// the tile origin; ld = row stride of both; kd = contraction depth.
// ---------------------------------------------------------------------------
__device__ __forceinline__ f32x16 nt64_acc(
    const __hip_bfloat16* __restrict__ A, const __hip_bfloat16* __restrict__ B,
    int kd, size_t ld, __hip_bfloat16* As, __hip_bfloat16* Bs)
{
    const int t    = threadIdx.x;
    const int lane = t & 63;
    const int wave = t >> 6;
    const int srow = lane >> 3;
    const int sw   = ((lane & 7) ^ srow) * 8;
    const int wm   = (wave >> 1) * 32;
    const int wn   = (wave & 1) * 32;
    const int fm   = lane & 31;
    const int fm7  = fm & 7;
    const int ghi  = lane >> 5;

    f32x16 acc = {};
    for (int k0 = 0; k0 < kd; k0 += 64) {
        __syncthreads();
#pragma unroll
        for (int i = 0; i < 2; ++i) {
            const int c = wave * 2 + i;
            async_copy16(A + (size_t)(c * 8 + srow) * ld + k0 + sw, As + c * 512);
            async_copy16(B + (size_t)(c * 8 + srow) * ld + k0 + sw, Bs + c * 512);
        }
        __syncthreads();
#pragma unroll
        for (int ks = 0; ks < 64; ks += 16) {
            const int pos = ((((ks >> 3) + ghi) ^ fm7) * 8);
            const s16x8 af = *(const s16x8*)(As + (wm + fm) * 64 + pos);
            const s16x8 bf = *(const s16x8*)(Bs + (wn + fm) * 64 + pos);
            acc = __builtin_amdgcn_mfma_f32_32x32x16_bf16(af, bf, acc, 0, 0, 0);
        }
    }
    return acc;
}

// direct store of the 64x64 tile (C pre-offset to tile origin)
template <typename OutT>
__device__ __forceinline__ void store_tile64(OutT* C, int ldc, const f32x16& acc) {
    const int lane = threadIdx.x & 63;
    const int wave = threadIdx.x >> 6;
    const int wm = (wave >> 1) * 32;
    const int wn = (wave & 1) * 32;
    const int col = wn + (lane & 31);
    const int rb  = 4 * (lane >> 5);
#pragma unroll
    for (int r = 0; r < 16; ++r) {
        const int row = wm + (r & 3) + 8 * (r >> 2) + rb;
        store_c(C, (size_t)row * ldc + col, acc[r]);
    }
}

// G_b = hcT_b @ hcT_b^T (Gram), bf16 out: grid (16, 16, 2) = 512 blocks
__global__ __launch_bounds__(256) void gemm_g(
    const __hip_bfloat16* __restrict__ hcT, __hip_bfloat16* __restrict__ G)
{
    __shared__ __align__(16) __hip_bfloat16 As[64 * 64];
    __shared__ __align__(16) __hip_bfloat16 Bs[64 * 64];
    const int b = blockIdx.z;
    const int m0 = blockIdx.x * 64, n0 = blockIdx.y * 64;
    const __hip_bfloat16* Ab = hcT + (size_t)b * HH * MM;
    f32x16 acc = nt64_acc(Ab + (size_t)m0 * MM, Ab + (size_t)n0 * MM, MM, MM, As, Bs);
    store_tile64(G + (size_t)b * HH * HH + (size_t)m0 * HH + n0, HH, acc);
}

// ---------------------------------------------------------------------------
// FUSED T_h = Wk_h G_b Wv_h^T, split over k'-tiles: grid (16, KH, BB) = 512
// Stage 1: Q[cc][i] = sum_k G[kt*64+cc][k] Wk_h[i][k]   (NT, K=1024; G symm)
// Stage 2: T[i][j] += sum_cc Q^T[i][cc] Wv_h[j][kt*64+cc] (16x16x32 MFMA)
// atomicAdd partials into Sbuf (zeroed by cvt). Clone of verified gemm_kvt
// phase-2 pattern (acc -> bf16 -> padded LDS -> small MFMA -> atomics).
// ---------------------------------------------------------------------------
#define LPP 72

__global__ __launch_bounds__(256) void gemm_vt(
    const __hip_bfloat16* __restrict__ wkb, const __hip_bfloat16* __restrict__ wvb,
    const __hip_bfloat16* __restrict__ G, float* __restrict__ S)
{
    __shared__ __align__(16) char smem[64 * LPP * 2 + 64 * 64 * 2];  // 17408 B
    __hip_bfloat16* As = (__hip_bfloat16*)smem;             // 8 KB (stage 1)
    __hip_bfloat16* Bs = (__hip_bfloat16*)(smem + 8192);    // 8 KB (stage 1)
    __hip_bfloat16* Pl = (__hip_bfloat16*)smem;             // 64 x LPP (stage 2)
    __hip_bfloat16* Wl = (__hip_bfloat16*)(smem + 64 * LPP * 2);  // 64x64 swz

    const int t    = threadIdx.x;
    const int lane = t & 63;
    const int wave = t >> 6;
    const int kt   = blockIdx.x;
    const int head = blockIdx.y;
    const int b    = blockIdx.z;

    const __hip_bfloat16* Arow = G + (size_t)b * HH * HH + (size_t)kt * 64 * HH;
    const __hip_bfloat16* Brow = wkb + (size_t)head * 64 * HH;

    f32x16 acc = nt64_acc(Arow, Brow, HH, HH, As, Bs);
    __syncthreads();   // all waves done reading As/Bs before Pl/Wl overwrite

    // Q[cc][i] -> Pl[i][cc] (4 consecutive cc per bf16x4, contiguous)
    {
        const int wm = (wave >> 1) * 32;     // cc quadrant
        const int wn = (wave & 1) * 32;      // i quadrant
        const int col_i = wn + (lane & 31);
        const int ghi4  = 4 * (lane >> 5);
#pragma unroll
        for (int g = 0; g < 4; ++g) {
            const int ccb = wm + 8 * g + ghi4;
            bf16x4_t o;
            o.x = __float2bfloat16(acc[4 * g + 0]);
            o.y = __float2bfloat16(acc[4 * g + 1]);
            o.z = __float2bfloat16(acc[4 * g + 2]);
            o.w = __float2bfloat16(acc[4 * g + 3]);
            *(bf16x4_t*)(Pl + col_i * LPP + ccb) = o;
        }
    }
    // stage Wv_h[:, kt-tile] (64x64) with pre-swizzled source columns
    {
        const int srow = lane >> 3;
        const int sw   = ((lane & 7) ^ srow) * 8;
#pragma unroll
        for (int i = 0; i < 2; ++i) {
            const int c = wave * 2 + i;
            async_copy16(wvb + (size_t)(head * 64 + c * 8 + srow) * HH + kt * 64 + sw,
                         Wl + c * 512);
        }
    }
    __syncthreads();

    const int fr  = lane & 15;
    const int fq  = (lane >> 4) * 8;
    const int wm2 = wave * 16;

    f32x4 acc2[4] = {};
#pragma unroll
    for (int kk = 0; kk < 64; kk += 32) {
        const s16x8 af = *(const s16x8*)(Pl + (wm2 + fr) * LPP + kk + fq);
#pragma unroll
        for (int nj = 0; nj < 4; ++nj) {
            const int row = nj * 16 + fr;
            const s16x8 bfv = *(const s16x8*)(
                Wl + row * 64 + ((((kk + fq) >> 3) ^ (row & 7)) << 3));
            acc2[nj] = __builtin_amdgcn_mfma_f32_16x16x32_bf16(af, bfv, acc2[nj], 0, 0, 0);
        }
    }

    float* Sg = S + ((size_t)b * KH + head) * 4096;
    const int er = (lane >> 4) * 4;
    const int ec = lane & 15;
#pragma unroll
    for (int nj = 0; nj < 4; ++nj)
#pragma unroll
        for (int rr = 0; rr < 4; ++rr)
            atomicAdd(&Sg[(wm2 + er + rr) * 64 + nj * 16 + ec], acc2[nj][rr]);
}

// F_b = W2_b @ Wq (via WqT), bf16 out: grid (16, 16, 2) = 512 blocks
__global__ __launch_bounds__(256) void gemm_f(
    const __hip_bfloat16* __restrict__ W2, const __hip_bfloat16* __restrict__ WqT,
    __hip_bfloat16* __restrict__ F)
{
    __shared__ __align__(16) __hip_bfloat16 As[64 * 64];
    __shared__ __align__(16) __hip_bfloat16 Bs[64 * 64];
    const int b = blockIdx.z;
    const int m0 = blockIdx.x * 64, n0 = blockIdx.y * 64;
    f32x16 acc = nt64_acc(W2 + (size_t)b * HH * HH + (size_t)m0 * HH,
                          WqT + (size_t)n0 * HH, HH, HH, As, Bs);
    store_tile64(F + (size_t)b * HH * HH + (size_t)m0 * HH + n0, HH, acc);
}

// ---------------------------------------------------------------------------
// 64x128-tile BK=64 NT GEMM body (verified rounds 7-10) — used for gemm_final
// ---------------------------------------------------------------------------
template <typename OutT>
__device__ __forceinline__ void gemm_nt_body64(
    const __hip_bfloat16* __restrict__ A,
    const __hip_bfloat16* __restrict__ Bm,
    OutT* __restrict__ C,
    __hip_bfloat16* As, __hip_bfloat16* Bs,
    int m0, int n0)
{
    const int t    = threadIdx.x;
    const int lane = t & 63;
    const int wave = t >> 6;

    const int srow = lane >> 3;
    const int sw   = ((lane & 7) ^ srow) * 8;

    const int wn  = wave * 32;
    const int fm  = lane & 31;
    const int fm7 = fm & 7;
    const int ghi = lane >> 5;

    f32x16 acc[2] = {};

    for (int k0 = 0; k0 < HH; k0 += 64) {
        __syncthreads();
        {
            const __hip_bfloat16* ag = A + (size_t)(m0 + wave * 16 + srow) * HH + k0 + sw;
            async_copy16(ag,          As + wave * 1024);
            async_copy16(ag + 8 * HH, As + wave * 1024 + 512);
        }
#pragma unroll
        for (int i = 0; i < 2; ++i) {
            const int c = wave * 2 + i;
            const __hip_bfloat16* bg = Bm + (size_t)(n0 + c * 16 + srow) * HH + k0 + sw;
            async_copy16(bg,          Bs + c * 1024);
            async_copy16(bg + 8 * HH, Bs + c * 1024 + 512);
        }
        __syncthreads();

#pragma unroll
        for (int ks = 0; ks < 64; ks += 16) {
            const int pos = ((((ks >> 3) + ghi) ^ fm7) * 8);
            s16x8 af[2], bf;
#pragma unroll
            for (int mi = 0; mi < 2; ++mi)
                af[mi] = *(const s16x8*)(As + (mi * 32 + fm) * 64 + pos);
            bf = *(const s16x8*)(Bs + (wn + fm) * 64 + pos);
#pragma unroll
            for (int mi = 0; mi < 2; ++mi)
                acc[mi] = __builtin_amdgcn_mfma_f32_32x32x16_bf16(
                    af[mi], bf, acc[mi], 0, 0, 0);
        }
    }

    const int ec = lane & 31;
    const int eb = (lane >> 5) * 4;
#pragma unroll
    for (int mi = 0; mi < 2; ++mi)
#pragma unroll
        for (int r = 0; r < 16; ++r) {
            const int m = m0 + mi * 32 + (r & 3) + 8 * (r >> 2) + eb;
            const int n = n0 + wn + ec;
            store_c(C, (size_t)m * HH + n, acc[mi][r]);
        }
}

// out_b = h_b @ F_b^T, fp32 out: grid (32, 8, 2) = 512 blocks
__global__ __launch_bounds__(256) void gemm_final(
    const __hip_bfloat16* __restrict__ hb, const __hip_bfloat16* __restrict__ F,
    float* __restrict__ outg)
{
    __shared__ __align__(16) __hip_bfloat16 As[64 * 64];
    __shared__ __align__(16) __hip_bfloat16 Bs[128 * 64];
    const int b = blockIdx.z;
    gemm_nt_body64<float>(hb + (size_t)b * MM * HH, F + (size_t)b * HH * HH,
                          outg + (size_t)b * MM * HH, As, Bs,
                          blockIdx.x * 64, blockIdx.y * 128);
}

// ---------------------------------------------------------------------------
// W2[b][n][h*64+dp] = sum_d Wo[n][h*64+d] * T[b,h,dp,d]   (bf16 out)
// grid (8, KH, BB), block 256  (verified rounds 2-10)
// ---------------------------------------------------------------------------
__global__ __launch_bounds__(256) void w2_fold(
    const __hip_bfloat16* __restrict__ Wo,
    const float* __restrict__ S,
    __hip_bfloat16* __restrict__ W2)
{
    __shared__ float Sl[64 * 68];
    __shared__ float Wl[128 * 68];
    const int t = threadIdx.x, head = blockIdx.y, b = blockIdx.z;
    const int n0 = blockIdx.x * 128;

    const float* Sg = S + ((size_t)b * KH + head) * 4096;
    for (int idx = t; idx < 4096; idx += 256) {
        const int dp = idx >> 6, d = idx & 63;
        Sl[d * 68 + dp] = Sg[idx];
    }
    for (int idx = t; idx < 1024; idx += 256) {
        const int r = idx >> 3, c8 = (idx & 7) * 8;
        s16x8 wv = *(const s16x8*)(Wo + (size_t)(n0 + r) * HH + head * 64 + c8);
#pragma unroll
        for (int j = 0; j < 8; ++j) {
            __hip_bfloat16 wb = *(((const __hip_bfloat16*)&wv) + j);
            Wl[r * 68 + c8 + j] = __bfloat162float(wb);
        }
    }
    __syncthreads();

    const int dpb = (t & 15) * 4;
    const int ng  = t >> 4;
    float acc[8][4] = {};
    for (int d0 = 0; d0 < 64; d0 += 4) {
        f32x4 sv[4];
#pragma unroll
        for (int r = 0; r < 4; ++r)
            sv[r] = *(const f32x4*)(Sl + (d0 + r) * 68 + dpb);
#pragma unroll
        for (int i = 0; i < 8; ++i) {
            const f32x4 wv = *(const f32x4*)(Wl + (ng + 16 * i) * 68 + d0);
#pragma unroll
            for (int r = 0; r < 4; ++r)
#pragma unroll
                for (int j = 0; j < 4; ++j)
                    acc[i][j] += wv[r] * sv[r][j];
        }
    }

#pragma unroll
    for (int i = 0; i < 8; ++i) {
        bf16x4_t o;
        o.x = __float2bfloat16(acc[i][0]);
        o.y = __float2bfloat16(acc[i][1]);
        o.z = __float2bfloat16(acc[i][2]);
        o.w = __float2bfloat16(acc[i][3]);
        *(bf16x4_t*)(W2 + (size_t)b * HH * HH + (size_t)(n0 + ng + 16 * i) * HH
                     + head * 64 + dpb) = o;
    }
}

// ---------------------------------------------------------------------------
extern "C" void kernel_launch(void* const* d_in, const int* in_sizes, int n_in,
                              void* d_out, int out_size, void* d_ws, size_t ws_size,
                              hipStream_t stream) {
    const float* h_f  = (const float*)d_in[0];
    const float* hc_f = (const float*)d_in[1];
    // d_in[2] = key_pe: DEAD (softmax result unused by reference output)
    const float* Wq_f = (const float*)d_in[3];
    const float* Wk_f = (const float*)d_in[4];
    const float* Wv_f = (const float*)d_in[5];
    const float* Wo_f = (const float*)d_in[6];
    float* out = (float*)d_out;

    const size_t act_b = (size_t)BB * MM * HH * 2;  // 8 MB
    const size_t w_b   = (size_t)HH * HH * 2;       // 2 MB
    char* ws = (char*)d_ws;
    __hip_bfloat16* hb   = (__hip_bfloat16*)(ws);                       // 8 MB
    __hip_bfloat16* hcT  = (__hip_bfloat16*)(ws + act_b);               // 8 MB ([b][k][m])
    __hip_bfloat16* wkb  = (__hip_bfloat16*)(ws + 2 * act_b);           // 2 MB
    __hip_bfloat16* wvb  = (__hip_bfloat16*)(ws + 2 * act_b + w_b);     // 2 MB
    __hip_bfloat16* wob  = (__hip_bfloat16*)(ws + 2 * act_b + 2 * w_b); // 2 MB
    __hip_bfloat16* wqt  = (__hip_bfloat16*)(ws + 2 * act_b + 3 * w_b); // 2 MB
    __hip_bfloat16* Gb   = (__hip_bfloat16*)(ws + 2 * act_b + 4 * w_b); // 4 MB (BB x 1024^2)
    float*          Sbuf = (float*)(ws + 2 * act_b + 6 * w_b);          // 512 KB
    __hip_bfloat16* W2   = (__hip_bfloat16*)(ws + 2 * act_b + 6 * w_b + (size_t)512 * 1024);  // 4 MB
    __hip_bfloat16* Fbuf = (__hip_bfloat16*)(ws + 2 * act_b + 8 * w_b + (size_t)512 * 1024);  // 4 MB

    const dim3 blk(256);

    // 0: all prep in one dispatch (converts + transposes + Sbuf zero)
    cvt_all<<<dim3(4096, 6), blk, 0, stream>>>(h_f, hc_f, Wk_f, Wv_f, Wo_f, Wq_f,
                                               hb, hcT, wkb, wvb, wob, wqt, Sbuf);

    // 1: G_b = hc_b^T hc_b (Gram), 512 blocks
    gemm_g<<<dim3(16, 16, BB), blk, 0, stream>>>(hcT, Gb);

    // 2: T_h = Wk_h G_b Wv_h^T fused (atomic partials into zeroed Sbuf), 512 blocks
    gemm_vt<<<dim3(16, KH, BB), blk, 0, stream>>>(wkb, wvb, Gb, Sbuf);

    // 3: W2 = blockdiag(T) folded into Wo
    w2_fold<<<dim3(8, KH, BB), blk, 0, stream>>>(wob, Sbuf, W2);

    // 4: F = W2 @ Wq (replaces the Q projection: out = h (W2 Wq)^T), 512 blocks
    gemm_f<<<dim3(16, 16, BB), blk, 0, stream>>>(W2, wqt, Fbuf);

    // 5: out = h @ F^T (fp32 out), 512 blocks
    gemm_final<<<dim3(32, 8, BB), blk, 0, stream>>>(hb, Fbuf, out);
}

// Round 4
// 169.076 us; speedup vs baseline: 1.1254x; 1.0488x over previous
//
#include <hip/hip_runtime.h>
#include <hip/hip_bf16.h>

// Problem dims (fixed): B=2, M=L=2048, H=1024, K_HEADS=16, D=64
// All inputs/output are FLOAT32; compute in bf16 MFMA with f32 accumulation.
// Algebra: softmax branch is dead; out = Q (K^T V) blockdiag Wo^T.
// Gram path: T_h = K_h^T V_h = Wk_h (hc^T hc) Wv_h^T:
//   G_b  = hcT_b @ hcT_b^T   (symmetric: 136 upper-tri tiles + transpose fill)
//   T_h  = Wk_h G_b Wv_h^T   (fused, split over k'-tiles, atomics into Sbuf)
//   W2[n][h*64+dp] = sum_d Wo[n][h*64+d] T[h][dp][d]
//   F_b = W2_b @ Wq ;  out_b = h_b @ F_b^T
// Round 13 = round 12 resubmit (container infra failure, no kernel signal):
// BK=128 (unroll-2, one barrier pair per 128-K) in all MFMA bodies;
// G symmetry (272 blocks); f/final at 64^2 tiles (512/1024 blocks).
#define BB 2
#define MM 2048
#define HH 1024
#define KH 16

typedef short s16x8 __attribute__((ext_vector_type(8)));
typedef float f32x4 __attribute__((ext_vector_type(4)));
typedef float f32x16 __attribute__((ext_vector_type(16)));

#define GLOBAL_AS __attribute__((address_space(1)))
#define LDS_AS    __attribute__((address_space(3)))

__device__ __forceinline__ void async_copy16(const void* g, void* l) {
    __builtin_amdgcn_global_load_lds((const GLOBAL_AS void*)g, (LDS_AS void*)l, 16, 0, 0);
}

struct __align__(8) bf16x4_t { __hip_bfloat16 x, y, z, w; };

// ---------------------------------------------------------------------------
// fused prep: fp32->bf16 converts + transposes + Sbuf zero: grid (4096, 6)
// seg 0: convert h; seg 1: transpose-convert hc -> hcT [b][k][m]
// seg 2/3/4: convert Wk/Wv/Wo; seg 5: Sbuf zero + transpose-convert Wq -> WqT
// ---------------------------------------------------------------------------
__global__ __launch_bounds__(256) void cvt_all(
    const float* __restrict__ h_f, const float* __restrict__ hc_f,
    const float* __restrict__ Wk_f, const float* __restrict__ Wv_f,
    const float* __restrict__ Wo_f, const float* __restrict__ Wq_f,
    __hip_bfloat16* __restrict__ hb, __hip_bfloat16* __restrict__ hcT,
    __hip_bfloat16* __restrict__ wkb, __hip_bfloat16* __restrict__ wvb,
    __hip_bfloat16* __restrict__ wob, __hip_bfloat16* __restrict__ wqt,
    float* __restrict__ Sz)
{
    __shared__ float Tl[64][65];
    const int seg = blockIdx.y;
    const int t = threadIdx.x;
    const int bx = blockIdx.x;

    if (seg == 1) {                        // hc -> hcT (per-b [1024][2048])
        if (bx >= BB * 512) return;
        const int b = bx >> 9;
        const int tile = bx & 511;
        const int m0 = (tile >> 4) * 64;   // 32 m-tiles
        const int k0 = (tile & 15) * 64;   // 16 k-tiles
        const int r = t >> 6;
        const int c = t & 63;
        const float* src = hc_f + (size_t)b * MM * HH;
#pragma unroll
        for (int i = 0; i < 64; i += 4)
            Tl[r + i][c] = src[(size_t)(m0 + r + i) * HH + k0 + c];
        __syncthreads();
        __hip_bfloat16* dst = hcT + (size_t)b * HH * MM;
        const int ml = (t & 15) * 4;
#pragma unroll
        for (int ii = 0; ii < 4; ++ii) {
            const int kl = (t >> 4) + 16 * ii;
            bf16x4_t o;
            o.x = __float2bfloat16(Tl[ml + 0][kl]);
            o.y = __float2bfloat16(Tl[ml + 1][kl]);
            o.z = __float2bfloat16(Tl[ml + 2][kl]);
            o.w = __float2bfloat16(Tl[ml + 3][kl]);
            *(bf16x4_t*)(dst + (size_t)(k0 + kl) * MM + m0 + ml) = o;
        }
        return;
    }
    if (seg == 5) {
        if (bx < 128) {                    // zero Sbuf: 131072 floats
            const int i = (bx * 256 + t) * 4;
            float4 z = {0.f, 0.f, 0.f, 0.f};
            *(float4*)(Sz + i) = z;
            return;
        }
        if (bx >= 384) return;             // Wq -> WqT (256 tiles)
        const int tile = bx - 128;
        const int j0 = (tile >> 4) * 64;
        const int k0 = (tile & 15) * 64;
        const int r = t >> 6;
        const int c = t & 63;
#pragma unroll
        for (int i = 0; i < 64; i += 4)
            Tl[r + i][c] = Wq_f[(size_t)(j0 + r + i) * HH + k0 + c];
        __syncthreads();
        const int ml = (t & 15) * 4;
#pragma unroll
        for (int ii = 0; ii < 4; ++ii) {
            const int kl = (t >> 4) + 16 * ii;
            bf16x4_t o;
            o.x = __float2bfloat16(Tl[ml + 0][kl]);
            o.y = __float2bfloat16(Tl[ml + 1][kl]);
            o.z = __float2bfloat16(Tl[ml + 2][kl]);
            o.w = __float2bfloat16(Tl[ml + 3][kl]);
            *(bf16x4_t*)(wqt + (size_t)(k0 + kl) * HH + j0 + ml) = o;
        }
        return;
    }
    const float* src;
    __hip_bfloat16* dst;
    int n;
    switch (seg) {
        case 0: src = h_f;  dst = hb;  n = BB * MM * HH; break;
        case 2: src = Wk_f; dst = wkb; n = HH * HH; break;
        case 3: src = Wv_f; dst = wvb; n = HH * HH; break;
        default: src = Wo_f; dst = wob; n = HH * HH; break;
    }
    const int i = (bx * 256 + t) * 4;
    if (i + 3 < n) {
        const float4 v = *(const float4*)(src + i);
        bf16x4_t o;
        o.x = __float2bfloat16(v.x);
        o.y = __float2bfloat16(v.y);
        o.z = __float2bfloat16(v.z);
        o.w = __float2bfloat16(v.w);
        *(bf16x4_t*)(dst + i) = o;
    }
}

// ---------------------------------------------------------------------------
// store helpers
// ---------------------------------------------------------------------------
__device__ __forceinline__ void store_c(__hip_bfloat16* C, size_t idx, float v) {
    C[idx] = __float2bfloat16(v);
}
__device__ __forceinline__ void store_c(float* C, size_t idx, float v) { C[idx] = v; }

// ---------------------------------------------------------------------------
// 64x64-tile BK=128 NT GEMM accumulate body (unroll-2 of the verified BK=64
// body: two 64-K sub-stages share ONE barrier pair -> half the vmcnt drains).
// 4 waves, each one 32x32 quadrant. A/B pre-offset to tile origin.
// As/Bs: 2 x 8KB each (16KB each).
// ---------------------------------------------------------------------------
__device__ __forceinline__ f32x16 nt64x2_acc(
    const __hip_bfloat16* __restrict__ A, const __hip_bfloat16* __restrict__ B,
    int kd, size_t ld, __hip_bfloat16* As, __hip_bfloat16* Bs)
{
    const int t    = threadIdx.x;
    const int lane = t & 63;
    const int wave = t >> 6;
    const int srow = lane >> 3;
    const int sw   = ((lane & 7) ^ srow) * 8;
    const int wm   = (wave >> 1) * 32;
    const int wn   = (wave & 1) * 32;
    const int fm   = lane & 31;
    const int fm7  = fm & 7;
    const int ghi  = lane >> 5;

    f32x16 acc = {};
    for (int k0 = 0; k0 < kd; k0 += 128) {
        __syncthreads();
#pragma unroll
        for (int h = 0; h < 2; ++h)
#pragma unroll
            for (int i = 0; i < 2; ++i) {
                const int c = wave * 2 + i;
                async_copy16(A + (size_t)(c * 8 + srow) * ld + k0 + 64 * h + sw,
                             As + h * 4096 + c * 512);
                async_copy16(B + (size_t)(c * 8 + srow) * ld + k0 + 64 * h + sw,
                             Bs + h * 4096 + c * 512);
            }
        __syncthreads();
#pragma unroll
        for (int h = 0; h < 2; ++h)
#pragma unroll
            for (int ks = 0; ks < 64; ks += 16) {
                const int pos = ((((ks >> 3) + ghi) ^ fm7) * 8);
                const s16x8 af = *(const s16x8*)(As + h * 4096 + (wm + fm) * 64 + pos);
                const s16x8 bf = *(const s16x8*)(Bs + h * 4096 + (wn + fm) * 64 + pos);
                acc = __builtin_amdgcn_mfma_f32_32x32x16_bf16(af, bf, acc, 0, 0, 0);
            }
    }
    return acc;
}

// direct store of the 64x64 tile (C pre-offset to tile origin)
template <typename OutT>
__device__ __forceinline__ void store_tile64(OutT* C, int ldc, const f32x16& acc) {
    const int lane = threadIdx.x & 63;
    const int wave = threadIdx.x >> 6;
    const int wm = (wave >> 1) * 32;
    const int wn = (wave & 1) * 32;
    const int col = wn + (lane & 31);
    const int rb  = 4 * (lane >> 5);
#pragma unroll
    for (int r = 0; r < 16; ++r) {
        const int row = wm + (r & 3) + 8 * (r >> 2) + rb;
        store_c(C, (size_t)row * ldc + col, acc[r]);
    }
}

// ---------------------------------------------------------------------------
// G_b = hcT_b @ hcT_b^T (Gram, SYMMETRIC): grid (136, 1, 2).
// Upper-triangle tiles (i<=j) computed; off-diagonal transposed via LDS
// bounce into the (j,i) tile so downstream reads see the full matrix.
// ---------------------------------------------------------------------------
__global__ __launch_bounds__(256) void gemm_g(
    const __hip_bfloat16* __restrict__ hcT, __hip_bfloat16* __restrict__ G)
{
    __shared__ __align__(16) char smem[32768];
    __hip_bfloat16* As = (__hip_bfloat16*)smem;
    __hip_bfloat16* Bs = (__hip_bfloat16*)(smem + 16384);
    __hip_bfloat16* Ts = (__hip_bfloat16*)smem;   // 64x72 bounce (9216 B)

    const int b = blockIdx.z;
    // decode upper-tri (i<=j) from linear blockIdx.x in [0,136)
    int i = 0, rem = blockIdx.x;
    while (rem >= 16 - i) { rem -= 16 - i; ++i; }
    const int j = i + rem;
    const int m0 = i * 64, n0 = j * 64;

    const __hip_bfloat16* Ab = hcT + (size_t)b * HH * MM;
    f32x16 acc = nt64x2_acc(Ab + (size_t)m0 * MM, Ab + (size_t)n0 * MM, MM, MM, As, Bs);

    __hip_bfloat16* Gb = G + (size_t)b * HH * HH;
    store_tile64(Gb + (size_t)m0 * HH + n0, HH, acc);

    if (i == j) return;

    // transpose fill of tile (j,i) via LDS bounce
    __syncthreads();   // all waves done reading As before Ts overwrite
    {
        const int lane = threadIdx.x & 63;
        const int wave = threadIdx.x >> 6;
        const int wm = (wave >> 1) * 32;
        const int wn = (wave & 1) * 32;
        const int col = wn + (lane & 31);
        const int rb  = 4 * (lane >> 5);
#pragma unroll
        for (int r = 0; r < 16; ++r) {
            const int row = wm + (r & 3) + 8 * (r >> 2) + rb;
            Ts[row * 72 + col] = __float2bfloat16(acc[r]);
        }
    }
    __syncthreads();
    {
        const int t = threadIdx.x;
        const int rp = t >> 2;            // 0..63: row of transposed tile
        const int c0 = (t & 3) * 16;      // 16 cols per thread
        __hip_bfloat16* dst = Gb + (size_t)(n0 + rp) * HH + m0 + c0;
#pragma unroll
        for (int kk = 0; kk < 4; ++kk) {
            bf16x4_t o;
            o.x = Ts[(c0 + 4 * kk + 0) * 72 + rp];
            o.y = Ts[(c0 + 4 * kk + 1) * 72 + rp];
            o.z = Ts[(c0 + 4 * kk + 2) * 72 + rp];
            o.w = Ts[(c0 + 4 * kk + 3) * 72 + rp];
            *(bf16x4_t*)(dst + 4 * kk) = o;
        }
    }
}

// ---------------------------------------------------------------------------
// FUSED T_h = Wk_h G_b Wv_h^T, split over k'-tiles: grid (16, KH, BB) = 512
// Stage 1: Q[cc][i] = sum_k G[kt*64+cc][k] Wk_h[i][k]   (NT, K=1024, BK=128)
// Stage 2: T[i][j] += sum_cc Q^T[i][cc] Wv_h[j][kt*64+cc] (16x16x32 MFMA)
// atomicAdd partials into Sbuf (zeroed by cvt). Verified rounds 8/11.
// ---------------------------------------------------------------------------
#define LPP 72

__global__ __launch_bounds__(256) void gemm_vt(
    const __hip_bfloat16* __restrict__ wkb, const __hip_bfloat16* __restrict__ wvb,
    const __hip_bfloat16* __restrict__ G, float* __restrict__ S)
{
    __shared__ __align__(16) char smem[32768];
    __hip_bfloat16* As = (__hip_bfloat16*)smem;             // 16 KB (stage 1)
    __hip_bfloat16* Bs = (__hip_bfloat16*)(smem + 16384);   // 16 KB (stage 1)
    __hip_bfloat16* Pl = (__hip_bfloat16*)smem;             // 64 x LPP (stage 2)
    __hip_bfloat16* Wl = (__hip_bfloat16*)(smem + 64 * LPP * 2);  // 64x64 swz

    const int t    = threadIdx.x;
    const int lane = t & 63;
    const int wave = t >> 6;
    const int kt   = blockIdx.x;
    const int head = blockIdx.y;
    const int b    = blockIdx.z;

    const __hip_bfloat16* Arow = G + (size_t)b * HH * HH + (size_t)kt * 64 * HH;
    const __hip_bfloat16* Brow = wkb + (size_t)head * 64 * HH;

    f32x16 acc = nt64x2_acc(Arow, Brow, HH, HH, As, Bs);
    __syncthreads();   // all waves done reading As/Bs before Pl/Wl overwrite

    // Q[cc][i] -> Pl[i][cc] (4 consecutive cc per bf16x4, contiguous)
    {
        const int wm = (wave >> 1) * 32;     // cc quadrant
        const int wn = (wave & 1) * 32;      // i quadrant
        const int col_i = wn + (lane & 31);
        const int ghi4  = 4 * (lane >> 5);
#pragma unroll
        for (int g = 0; g < 4; ++g) {
            const int ccb = wm + 8 * g + ghi4;
            bf16x4_t o;
            o.x = __float2bfloat16(acc[4 * g + 0]);
            o.y = __float2bfloat16(acc[4 * g + 1]);
            o.z = __float2bfloat16(acc[4 * g + 2]);
            o.w = __float2bfloat16(acc[4 * g + 3]);
            *(bf16x4_t*)(Pl + col_i * LPP + ccb) = o;
        }
    }
    // stage Wv_h[:, kt-tile] (64x64) with pre-swizzled source columns
    {
        const int srow = lane >> 3;
        const int sw   = ((lane & 7) ^ srow) * 8;
#pragma unroll
        for (int i = 0; i < 2; ++i) {
            const int c = wave * 2 + i;
            async_copy16(wvb + (size_t)(head * 64 + c * 8 + srow) * HH + kt * 64 + sw,
                         Wl + c * 512);
        }
    }
    __syncthreads();

    const int fr  = lane & 15;
    const int fq  = (lane >> 4) * 8;
    const int wm2 = wave * 16;

    f32x4 acc2[4] = {};
#pragma unroll
    for (int kk = 0; kk < 64; kk += 32) {
        const s16x8 af = *(const s16x8*)(Pl + (wm2 + fr) * LPP + kk + fq);
#pragma unroll
        for (int nj = 0; nj < 4; ++nj) {
            const int row = nj * 16 + fr;
            const s16x8 bfv = *(const s16x8*)(
                Wl + row * 64 + ((((kk + fq) >> 3) ^ (row & 7)) << 3));
            acc2[nj] = __builtin_amdgcn_mfma_f32_16x16x32_bf16(af, bfv, acc2[nj], 0, 0, 0);
        }
    }

    float* Sg = S + ((size_t)b * KH + head) * 4096;
    const int er = (lane >> 4) * 4;
    const int ec = lane & 15;
#pragma unroll
    for (int nj = 0; nj < 4; ++nj)
#pragma unroll
        for (int rr = 0; rr < 4; ++rr)
            atomicAdd(&Sg[(wm2 + er + rr) * 64 + nj * 16 + ec], acc2[nj][rr]);
}

// F_b = W2_b @ Wq (via WqT), bf16 out: grid (16, 16, 2) = 512 blocks
__global__ __launch_bounds__(256) void gemm_f(
    const __hip_bfloat16* __restrict__ W2, const __hip_bfloat16* __restrict__ WqT,
    __hip_bfloat16* __restrict__ F)
{
    __shared__ __align__(16) char smem[32768];
    __hip_bfloat16* As = (__hip_bfloat16*)smem;
    __hip_bfloat16* Bs = (__hip_bfloat16*)(smem + 16384);
    const int b = blockIdx.z;
    const int m0 = blockIdx.x * 64, n0 = blockIdx.y * 64;
    f32x16 acc = nt64x2_acc(W2 + (size_t)b * HH * HH + (size_t)m0 * HH,
                            WqT + (size_t)n0 * HH, HH, HH, As, Bs);
    store_tile64(F + (size_t)b * HH * HH + (size_t)m0 * HH + n0, HH, acc);
}

// out_b = h_b @ F_b^T, fp32 out: grid (32, 16, 2) = 1024 blocks
__global__ __launch_bounds__(256) void gemm_final(
    const __hip_bfloat16* __restrict__ hb, const __hip_bfloat16* __restrict__ F,
    float* __restrict__ outg)
{
    __shared__ __align__(16) char smem[32768];
    __hip_bfloat16* As = (__hip_bfloat16*)smem;
    __hip_bfloat16* Bs = (__hip_bfloat16*)(smem + 16384);
    const int b = blockIdx.z;
    const int m0 = blockIdx.x * 64, n0 = blockIdx.y * 64;
    f32x16 acc = nt64x2_acc(hb + (size_t)b * MM * HH + (size_t)m0 * HH,
                            F + (size_t)b * HH * HH + (size_t)n0 * HH, HH, HH, As, Bs);
    store_tile64(outg + (size_t)b * MM * HH + (size_t)m0 * HH + n0, HH, acc);
}

// ---------------------------------------------------------------------------
// W2[b][n][h*64+dp] = sum_d Wo[n][h*64+d] * T[b,h,dp,d]   (bf16 out)
// grid (8, KH, BB), block 256  (verified rounds 2-12)
// ---------------------------------------------------------------------------
__global__ __launch_bounds__(256) void w2_fold(
    const __hip_bfloat16* __restrict__ Wo,
    const float* __restrict__ S,
    __hip_bfloat16* __restrict__ W2)
{
    __shared__ float Sl[64 * 68];
    __shared__ float Wl[128 * 68];
    const int t = threadIdx.x, head = blockIdx.y, b = blockIdx.z;
    const int n0 = blockIdx.x * 128;

    const float* Sg = S + ((size_t)b * KH + head) * 4096;
    for (int idx = t; idx < 4096; idx += 256) {
        const int dp = idx >> 6, d = idx & 63;
        Sl[d * 68 + dp] = Sg[idx];
    }
    for (int idx = t; idx < 1024; idx += 256) {
        const int r = idx >> 3, c8 = (idx & 7) * 8;
        s16x8 wv = *(const s16x8*)(Wo + (size_t)(n0 + r) * HH + head * 64 + c8);
#pragma unroll
        for (int j = 0; j < 8; ++j) {
            __hip_bfloat16 wb = *(((const __hip_bfloat16*)&wv) + j);
            Wl[r * 68 + c8 + j] = __bfloat162float(wb);
        }
    }
    __syncthreads();

    const int dpb = (t & 15) * 4;
    const int ng  = t >> 4;
    float acc[8][4] = {};
    for (int d0 = 0; d0 < 64; d0 += 4) {
        f32x4 sv[4];
#pragma unroll
        for (int r = 0; r < 4; ++r)
            sv[r] = *(const f32x4*)(Sl + (d0 + r) * 68 + dpb);
#pragma unroll
        for (int i = 0; i < 8; ++i) {
            const f32x4 wv = *(const f32x4*)(Wl + (ng + 16 * i) * 68 + d0);
#pragma unroll
            for (int r = 0; r < 4; ++r)
#pragma unroll
                for (int j = 0; j < 4; ++j)
                    acc[i][j] += wv[r] * sv[r][j];
        }
    }

#pragma unroll
    for (int i = 0; i < 8; ++i) {
        bf16x4_t o;
        o.x = __float2bfloat16(acc[i][0]);
        o.y = __float2bfloat16(acc[i][1]);
        o.z = __float2bfloat16(acc[i][2]);
        o.w = __float2bfloat16(acc[i][3]);
        *(bf16x4_t*)(W2 + (size_t)b * HH * HH + (size_t)(n0 + ng + 16 * i) * HH
                     + head * 64 + dpb) = o;
    }
}

// ---------------------------------------------------------------------------
extern "C" void kernel_launch(void* const* d_in, const int* in_sizes, int n_in,
                              void* d_out, int out_size, void* d_ws, size_t ws_size,
                              hipStream_t stream) {
    const float* h_f  = (const float*)d_in[0];
    const float* hc_f = (const float*)d_in[1];
    // d_in[2] = key_pe: DEAD (softmax result unused by reference output)
    const float* Wq_f = (const float*)d_in[3];
    const float* Wk_f = (const float*)d_in[4];
    const float* Wv_f = (const float*)d_in[5];
    const float* Wo_f = (const float*)d_in[6];
    float* out = (float*)d_out;

    const size_t act_b = (size_t)BB * MM * HH * 2;  // 8 MB
    const size_t w_b   = (size_t)HH * HH * 2;       // 2 MB
    char* ws = (char*)d_ws;
    __hip_bfloat16* hb   = (__hip_bfloat16*)(ws);                       // 8 MB
    __hip_bfloat16* hcT  = (__hip_bfloat16*)(ws + act_b);               // 8 MB ([b][k][m])
    __hip_bfloat16* wkb  = (__hip_bfloat16*)(ws + 2 * act_b);           // 2 MB
    __hip_bfloat16* wvb  = (__hip_bfloat16*)(ws + 2 * act_b + w_b);     // 2 MB
    __hip_bfloat16* wob  = (__hip_bfloat16*)(ws + 2 * act_b + 2 * w_b); // 2 MB
    __hip_bfloat16* wqt  = (__hip_bfloat16*)(ws + 2 * act_b + 3 * w_b); // 2 MB
    __hip_bfloat16* Gb   = (__hip_bfloat16*)(ws + 2 * act_b + 4 * w_b); // 4 MB (BB x 1024^2)
    float*          Sbuf = (float*)(ws + 2 * act_b + 6 * w_b);          // 512 KB
    __hip_bfloat16* W2   = (__hip_bfloat16*)(ws + 2 * act_b + 6 * w_b + (size_t)512 * 1024);  // 4 MB
    __hip_bfloat16* Fbuf = (__hip_bfloat16*)(ws + 2 * act_b + 8 * w_b + (size_t)512 * 1024);  // 4 MB

    const dim3 blk(256);

    // 0: all prep in one dispatch (converts + transposes + Sbuf zero)
    cvt_all<<<dim3(4096, 6), blk, 0, stream>>>(h_f, hc_f, Wk_f, Wv_f, Wo_f, Wq_f,
                                               hb, hcT, wkb, wvb, wob, wqt, Sbuf);

    // 1: G_b = hc_b^T hc_b (Gram, symmetric: upper-tri + transpose fill)
    gemm_g<<<dim3(136, 1, BB), blk, 0, stream>>>(hcT, Gb);

    // 2: T_h = Wk_h G_b Wv_h^T fused (atomic partials into zeroed Sbuf)
    gemm_vt<<<dim3(16, KH, BB), blk, 0, stream>>>(wkb, wvb, Gb, Sbuf);

    // 3: W2 = blockdiag(T) folded into Wo
    w2_fold<<<dim3(8, KH, BB), blk, 0, stream>>>(wob, Sbuf, W2);

    // 4: F = W2 @ Wq (replaces the Q projection: out = h (W2 Wq)^T)
    gemm_f<<<dim3(16, 16, BB), blk, 0, stream>>>(W2, wqt, Fbuf);

    // 5: out = h @ F^T (fp32 out)
    gemm_final<<<dim3(32, 16, BB), blk, 0, stream>>>(hb, Fbuf, out);
}